// Round 12
// baseline (330.198 us; speedup 1.0000x reference)
//
#include <hip/hip_runtime.h>
#include <hip/hip_bf16.h>
#include <stdint.h>

#define NROWS 8192
#define DIM 512

typedef short bf16x8 __attribute__((ext_vector_type(8)));
typedef float f32x4 __attribute__((ext_vector_type(4)));

__device__ __forceinline__ unsigned short f2bf(float f) {
    union { float f; uint32_t u; } c; c.f = f;
    uint32_t u = c.u;
    return (unsigned short)((u + 0x7FFFu + ((u >> 16) & 1u)) >> 16);
}

__device__ __forceinline__ void gload16(const unsigned short* g, unsigned short* l) {
    __builtin_amdgcn_global_load_lds((const __attribute__((address_space(1))) void*)g,
                                     (__attribute__((address_space(3))) void*)l,
                                     16, 0, 0);
}

// lin(a,b) for a<=b in 0..31: inverse of the supertile triangle decode.
__device__ __forceinline__ int linof(int a, int b) {
    constexpr int base[4][4] = {{0, 36, 100, 164},
                                {0, 228, 264, 328},
                                {0, 0, 392, 428},
                                {0, 0, 0, 492}};
    const int SI = a >> 3, SJ = b >> 3, x = a & 7, y = b & 7;
    int inner;
    if (SI == SJ) inner = (x << 3) - ((x * (x - 1)) >> 1) + (y - x);
    else          inner = (x << 3) + y;
    return base[SI][SJ] + inner;
}

// ---------------- Kernel 1: L2-normalize rows -> bf16; zero done-counter ----------------
__global__ __launch_bounds__(256) void knorm(const float* __restrict__ in,
                                             unsigned short* __restrict__ out,
                                             int* __restrict__ cnt) {
    if (blockIdx.x == 0 && threadIdx.x == 0) cnt[0] = 0;
    const int row  = (blockIdx.x << 2) + (threadIdx.x >> 6);
    const int lane = threadIdx.x & 63;
    const float4* src = (const float4*)(in + (size_t)row * DIM);
    float4 a = src[lane];
    float4 b = src[lane + 64];
    float ss = a.x*a.x + a.y*a.y + a.z*a.z + a.w*a.w
             + b.x*b.x + b.y*b.y + b.z*b.z + b.w*b.w;
    #pragma unroll
    for (int m = 1; m < 64; m <<= 1) ss += __shfl_xor(ss, m);
    const float inv = 1.0f / sqrtf(ss);
    ushort4* dst = (ushort4*)(out + (size_t)row * DIM);
    ushort4 o;
    o.x = f2bf(a.x*inv); o.y = f2bf(a.y*inv); o.z = f2bf(a.z*inv); o.w = f2bf(a.w*inv);
    dst[lane] = o;
    o.x = f2bf(b.x*inv); o.y = f2bf(b.y*inv); o.z = f2bf(b.z*inv); o.w = f2bf(b.w*inv);
    dst[lane + 64] = o;
}

// ---------------- Kernel 2: R9 main loop + partials + fused last-block finalize ----------
// Main loop & partial epilogue IDENTICAL to R9 (measured best: 56.4us, 628 TF,
// 0 conflicts, FETCH 19.4 MB). Added: last-block-done gather replaces the kred
// launch. Writers: __threadfence (release) -> atomicAdd(cnt). The block
// observing 527 re-fences (acquire; device scope covers cross-XCD L2
// non-coherence) and computes the final loss with its 1024 threads,
// single-store to out[0] (no atomic, no pre-zero needed).
__global__ __launch_bounds__(1024, 1) void kgemm(const unsigned short* __restrict__ E,
                                                 float* __restrict__ part,
                                                 float* __restrict__ pospart,
                                                 int* __restrict__ cnt,
                                                 float* __restrict__ out) {
    __shared__ unsigned short lds[2][2][256 * 32];

    const int tid = threadIdx.x;
    const int w = tid >> 6;
    const int l = tid & 63;

    // ---- block id -> (bi, bj): supertile triangle decode ----
    const int lin = (int)((blockIdx.x & 7) * 66 + (blockIdx.x >> 3));
    int rem = lin;
    int SI = -1, SJ = -1;
    #pragma unroll
    for (int s = 0; s < 10; s++) {
        constexpr int si_t[10] = {0,0,0,0,1,1,1,2,2,3};
        constexpr int sj_t[10] = {0,1,2,3,1,2,3,2,3,3};
        const int sz = (si_t[s] == sj_t[s]) ? 36 : 64;
        if (SI < 0) {
            if (rem < sz) { SI = si_t[s]; SJ = sj_t[s]; }
            else rem -= sz;
        }
    }
    int bi, bj;
    if (SI == SJ) {
        int x = 0;
        while (rem >= 8 - x) { rem -= 8 - x; x++; }
        bi = (SI << 3) + x; bj = (SI << 3) + x + rem;
    } else {
        bi = (SI << 3) + (rem >> 3);
        bj = (SJ << 3) + (rem & 7);
    }

    const int brow = bi << 8;
    const int bcol = bj << 8;
    const int wr = (w >> 2) << 6;
    const int wc = (w & 3) << 6;

    f32x4 acc[4][4];
    #pragma unroll
    for (int i = 0; i < 4; i++)
        #pragma unroll
        for (int j = 0; j < 4; j++) acc[i][j] = (f32x4)0.0f;

    const int g_src = (l & 3) ^ ((l >> 3) & 3);
    const int r_st  = (w << 4) + (l >> 2);

    auto STAGE = [&](int buf, int kt) {
        const size_t colb = (size_t)((kt << 5) + (g_src << 3));
        gload16(E + (size_t)(brow + r_st) * DIM + colb, &lds[buf][0][w << 9]);
        gload16(E + (size_t)(bcol + r_st) * DIM + colb, &lds[buf][1][w << 9]);
    };

    const int sgk = (((l >> 4) ^ ((l >> 1) & 3)) << 3);

    auto COMPUTE = [&](int buf) {
        const unsigned short* sA = lds[buf][0];
        const unsigned short* sB = lds[buf][1];
        bf16x8 aF[4], bF[4];
        #pragma unroll
        for (int mi = 0; mi < 4; mi++) {
            const int rr = wr + (mi << 4) + (l & 15);
            aF[mi] = *(const bf16x8*)&sA[(rr << 5) + sgk];
        }
        #pragma unroll
        for (int ni = 0; ni < 4; ni++) {
            const int rr = wc + (ni << 4) + (l & 15);
            bF[ni] = *(const bf16x8*)&sB[(rr << 5) + sgk];
        }
        #pragma unroll
        for (int mi = 0; mi < 4; mi++)
            #pragma unroll
            for (int ni = 0; ni < 4; ni++)
                acc[mi][ni] = __builtin_amdgcn_mfma_f32_16x16x32_bf16(
                    aF[mi], bF[ni], acc[mi][ni], 0, 0, 0);
    };

    STAGE(0, 0);
    #pragma unroll
    for (int kt = 0; kt < 16; kt++) {
        if (kt > 0) __builtin_amdgcn_s_barrier();
        if (kt < 15) {
            STAGE((kt + 1) & 1, kt + 1);
            asm volatile("s_waitcnt vmcnt(2)" ::: "memory");
        } else {
            asm volatile("s_waitcnt vmcnt(0)" ::: "memory");
        }
        __builtin_amdgcn_sched_barrier(0);
        __builtin_amdgcn_s_barrier();
        COMPUTE(kt & 1);
    }

    // ---- epilogue: exp(10*dot - 10), classify, LDS assemble, streaming store ----
    float* lds_row = (float*)&lds[0][0][0];       // [4][256]
    float* lds_col = lds_row + 1024;              // [4][256]
    float* lds_pos = lds_row + 2048;              // [4][256]

    __syncthreads();   // all COMPUTE reads done before LDS reuse

    if (bi == bj) {
        #pragma unroll
        for (int mi = 0; mi < 4; mi++) {
            #pragma unroll
            for (int r = 0; r < 4; r++) {
                const int lrow = wr + (mi << 4) + ((l >> 4) << 2) + r;
                const int gi = brow + lrow;
                float p = 0.0f, n = 0.0f;
                #pragma unroll
                for (int ni = 0; ni < 4; ni++) {
                    const int gj = bcol + wc + (ni << 4) + (l & 15);
                    const float e = __expf(fmaf(acc[mi][ni][r], 10.0f, -10.0f));
                    if (gi == gj) {
                    } else if ((gi >> 2) == (gj >> 2)) {
                        p += e;
                    } else {
                        n += e;
                    }
                }
                #pragma unroll
                for (int m = 1; m < 16; m <<= 1) {
                    n += __shfl_xor(n, m);
                    p += __shfl_xor(p, m);
                }
                if ((l & 15) == 0) {
                    lds_row[((w & 3) << 8) + lrow] = n;
                    lds_pos[((w & 3) << 8) + lrow] = p;
                }
            }
        }
    } else {
        float c[4] = {0.0f, 0.0f, 0.0f, 0.0f};
        #pragma unroll
        for (int mi = 0; mi < 4; mi++) {
            #pragma unroll
            for (int r = 0; r < 4; r++) {
                const int lrow = wr + (mi << 4) + ((l >> 4) << 2) + r;
                float n = 0.0f;
                #pragma unroll
                for (int ni = 0; ni < 4; ni++) {
                    const float e = __expf(fmaf(acc[mi][ni][r], 10.0f, -10.0f));
                    n += e;
                    c[ni] += e;
                }
                #pragma unroll
                for (int m = 1; m < 16; m <<= 1) n += __shfl_xor(n, m);
                if ((l & 15) == 0) lds_row[((w & 3) << 8) + lrow] = n;
            }
        }
        #pragma unroll
        for (int ni = 0; ni < 4; ni++) {
            c[ni] += __shfl_xor(c[ni], 16);
            c[ni] += __shfl_xor(c[ni], 32);
            if ((l >> 4) == 0)
                lds_col[((w >> 2) << 8) + wc + (ni << 4) + l] = c[ni];
        }
    }
    __syncthreads();

    if (tid < 256) {
        const float s = lds_row[tid] + lds_row[256 + tid]
                      + lds_row[512 + tid] + lds_row[768 + tid];
        part[((size_t)lin << 9) + tid] = s;
    } else if (tid < 512) {
        if (bi != bj) {
            const int cc = tid - 256;
            const float s = lds_col[cc] + lds_col[256 + cc]
                          + lds_col[512 + cc] + lds_col[768 + cc];
            part[((size_t)lin << 9) + 256 + cc] = s;
        }
    } else if (tid < 768) {
        if (bi == bj) {
            const int rr = tid - 512;
            const float s = lds_pos[rr] + lds_pos[256 + rr]
                          + lds_pos[512 + rr] + lds_pos[768 + rr];
            pospart[(bi << 8) + rr] = s;
        }
    }

    // ---- last-block-done finalization (replaces the kred launch) ----
    __threadfence();                              // release partials (device scope)
    __shared__ int isLast;
    if (tid == 0) isLast = (atomicAdd(cnt, 1) == 527);
    __syncthreads();
    if (!isLast) return;
    __threadfence();                              // acquire all blocks' partials

    float s = 0.0f;
    for (int r = tid; r < NROWS; r += 1024) {
        const int T = r >> 8, rr = r & 255;
        float n = 0.0f;
        for (int b2 = T; b2 < 32; b2++)
            n += part[((size_t)linof(T, b2) << 9) + rr];
        for (int b1 = 0; b1 < T; b1++)
            n += part[((size_t)linof(b1, T) << 9) + 256 + rr];
        const float p = pospart[(T << 8) + rr];
        s += __logf(p + n + 1e-8f) - __logf(p);
    }
    #pragma unroll
    for (int m = 1; m < 64; m <<= 1) s += __shfl_xor(s, m);
    __shared__ float red[16];
    if ((tid & 63) == 0) red[tid >> 6] = s;
    __syncthreads();
    if (tid == 0) {
        float t = 0.0f;
        #pragma unroll
        for (int i = 0; i < 16; i++) t += red[i];
        out[0] = t * (1.0f / (float)NROWS);
    }
}

extern "C" void kernel_launch(void* const* d_in, const int* in_sizes, int n_in,
                              void* d_out, int out_size, void* d_ws, size_t ws_size,
                              hipStream_t stream) {
    (void)in_sizes; (void)n_in; (void)out_size; (void)ws_size;
    const float* emb = (const float*)d_in[0];
    unsigned short* En = (unsigned short*)d_ws;                          // 8 MB bf16
    float* pospart = (float*)((char*)d_ws + (size_t)NROWS * DIM * 2);    // 32 KB
    float* part    = pospart + 32 * 256;                                 // 1.05 MB
    int*   cnt     = (int*)(part + 528 * 512);                           // 4 B

    knorm<<<NROWS / 4, 256, 0, stream>>>(emb, En, cnt);
    kgemm<<<528, 1024, 0, stream>>>(En, part, pospart, cnt, (float*)d_out);
}